// Round 7
// baseline (292.462 us; speedup 1.0000x reference)
//
#include <hip/hip_runtime.h>
#include <hip/hip_bf16.h>
#include <stdint.h>

#define B_   4
#define T_   2048
#define D_   1024
#define H_   16
#define HD_  64
#define MROWS (B_*T_)      // 8192
#define NQKV  3072
#define NST  (T_/64)       // 32 s-tiles per head

typedef __attribute__((ext_vector_type(8))) short  short8;   // 8 x bf16
typedef __attribute__((ext_vector_type(4))) short  bf16x4;   // 4 x bf16 (avoid HIP's short4)
typedef __attribute__((ext_vector_type(4))) float  floatx4;

#define QSCALE 0.1803368801111244f   // log2(e)/sqrt(64)

__device__ inline void async_copy16(const __hip_bfloat16* g, __hip_bfloat16* l) {
  __builtin_amdgcn_global_load_lds(
      (const __attribute__((address_space(1))) void*)g,
      (__attribute__((address_space(3))) void*)l, 16, 0, 0);
}

// K=16 bf16 MFMA (exists on gfx950 as ..._16x16x16bf16_1k; fallback keeps it compiling)
__device__ inline floatx4 mfma16(bf16x4 a, bf16x4 b, floatx4 c) {
#if __has_builtin(__builtin_amdgcn_mfma_f32_16x16x16bf16_1k)
  return __builtin_amdgcn_mfma_f32_16x16x16bf16_1k(a, b, c, 0, 0, 0);
#elif __has_builtin(__builtin_amdgcn_mfma_f32_16x16x16_bf16)
  return __builtin_amdgcn_mfma_f32_16x16x16_bf16(a, b, c, 0, 0, 0);
#else
  short8 a8 = (short8){a[0], a[1], a[2], a[3], 0, 0, 0, 0};
  short8 b8 = (short8){b[0], b[1], b[2], b[3], 0, 0, 0, 0};
  return __builtin_amdgcn_mfma_f32_16x16x32_bf16(a8, b8, c, 0, 0, 0);
#endif
}

// ---------------- conversion kernels ----------------

__global__ void convert_bf16(const float* __restrict__ in, __hip_bfloat16* __restrict__ out, int n) {
  int i = (blockIdx.x * blockDim.x + threadIdx.x) * 4;
  if (i < n) {
    float4 v = *(const float4*)(in + i);
    out[i + 0] = __float2bfloat16(v.x);
    out[i + 1] = __float2bfloat16(v.y);
    out[i + 2] = __float2bfloat16(v.z);
    out[i + 3] = __float2bfloat16(v.w);
  }
}

__global__ void transpose_w(const float* __restrict__ Wq, const float* __restrict__ Wk,
                            const float* __restrict__ Wv, __hip_bfloat16* __restrict__ wqkv) {
  __shared__ __hip_bfloat16 tile[64][65];
  const int t = threadIdx.x;
  const int d0 = blockIdx.x * 64;
  const int wh = blockIdx.y;           // 0..47
  const int which = wh >> 4, h = wh & 15;
  const float* W = (which == 0) ? Wq : ((which == 1) ? Wk : Wv);
  const float* base = W + (size_t)h * D_ * HD_;
#pragma unroll
  for (int i = 0; i < 16; i++) {
    int e = i * 256 + t;
    int dr = e >> 6, hd = e & 63;
    tile[dr][hd] = __float2bfloat16(base[(size_t)(d0 + dr) * HD_ + hd]);
  }
  __syncthreads();
#pragma unroll
  for (int i = 0; i < 16; i++) {
    int e = i * 256 + t;
    int hd = e >> 6, dr = e & 63;
    wqkv[(size_t)(which * 1024 + h * 64 + hd) * D_ + d0 + dr] = tile[dr][hd];
  }
}

// ---------------- repack K,V into fragment-contiguous tiles ----------------
__global__ void repack_kv(const __hip_bfloat16* __restrict__ qkv,
                          __hip_bfloat16* __restrict__ kpack, __hip_bfloat16* __restrict__ vpack) {
  __shared__ __hip_bfloat16 Ks[64][72];
  __shared__ __hip_bfloat16 Vs[64][72];
  const int tid = threadIdx.x;
  const int st = blockIdx.x, bh = blockIdx.y;
  const int b = bh >> 4, h = bh & 15;
#pragma unroll
  for (int p = 0; p < 2; p++) {
    int c = p * 256 + tid;           // 512 chunks of 16B per matrix
    int row = c >> 3, col8 = c & 7;
    const __hip_bfloat16* src = qkv + (size_t)(b * T_ + st * 64 + row) * NQKV + h * HD_ + col8 * 8;
    *(uint4*)&Ks[row][col8 * 8] = *(const uint4*)(src + 1024);
    *(uint4*)&Vs[row][col8 * 8] = *(const uint4*)(src + 2048);
  }
  __syncthreads();
  const size_t base = ((size_t)bh * NST + st) * 8 * 512;
#pragma unroll
  for (int p = 0; p < 2; p++) {
    int pair = p * 256 + tid;        // 8 chunks x 64 lanes
    int c = pair >> 6, l = pair & 63;
    int lq = l & 15, q = l >> 4;
    int ni = c >> 1, half = c & 1;
    short8 v = *(const short8*)&Ks[ni * 16 + lq][half * 32 + q * 8];
    *(short8*)(kpack + base + (size_t)c * 512 + l * 8) = v;
  }
#pragma unroll
  for (int p = 0; p < 2; p++) {
    int pair = p * 256 + tid;
    int c = pair >> 6, l = pair & 63;
    int lq = l & 15, q = l >> 4;
    int m = c >> 2, nt = c & 3;
    __hip_bfloat16 tmp[8];
#pragma unroll
    for (int half = 0; half < 2; half++)
#pragma unroll
      for (int j = 0; j < 4; j++)
        tmp[half * 4 + j] = Vs[(2 * m + half) * 16 + q * 4 + j][nt * 16 + lq];
    *(short8*)(vpack + base + (size_t)c * 512 + l * 8) = *(short8*)tmp;
  }
}

// ---------------- GEMM: C = A[M,K] * Bt[N,K]^T ----------------
template <int EPI>
__launch_bounds__(256, 2)
__global__ void gemm_bt(const __hip_bfloat16* __restrict__ A, const __hip_bfloat16* __restrict__ Bt,
                        __hip_bfloat16* __restrict__ Cb, float* __restrict__ Cf,
                        const float* __restrict__ bias, int M, int N, int K, float qscale) {
  __shared__ __hip_bfloat16 As[128 * 32];
  __shared__ __hip_bfloat16 Bs[128 * 32];
  const int tid = threadIdx.x;
  const int w = tid >> 6, lane = tid & 63;
  const int lq = lane & 15, quad = lane >> 4;
  const int wr = w >> 1, wc = w & 1;
  const int m0 = blockIdx.x * 128, n0 = blockIdx.y * 128;

  floatx4 acc[4][4];
#pragma unroll
  for (int i = 0; i < 4; i++)
#pragma unroll
    for (int j = 0; j < 4; j++) acc[i][j] = (floatx4){0.f, 0.f, 0.f, 0.f};

  for (int k0 = 0; k0 < K; k0 += 32) {
    __syncthreads();
#pragma unroll
    for (int ph = 0; ph < 2; ++ph) {
      int c = ph * 256 + tid;
      int row = c >> 2, col8 = c & 3;
      async_copy16(A + (size_t)(m0 + row) * K + k0 + col8 * 8, As + c * 8);
      async_copy16(Bt + (size_t)(n0 + row) * K + k0 + col8 * 8, Bs + c * 8);
    }
    __syncthreads();
    short8 af[4], bf[4];
#pragma unroll
    for (int mi = 0; mi < 4; mi++)
      af[mi] = *(const short8*)(As + (wr * 64 + mi * 16 + lq) * 32 + quad * 8);
#pragma unroll
    for (int ni = 0; ni < 4; ni++)
      bf[ni] = *(const short8*)(Bs + (wc * 64 + ni * 16 + lq) * 32 + quad * 8);
#pragma unroll
    for (int mi = 0; mi < 4; mi++)
#pragma unroll
      for (int ni = 0; ni < 4; ni++)
        acc[mi][ni] = __builtin_amdgcn_mfma_f32_16x16x32_bf16(af[mi], bf[ni], acc[mi][ni], 0, 0, 0);
  }

#pragma unroll
  for (int mi = 0; mi < 4; mi++) {
#pragma unroll
    for (int ni = 0; ni < 4; ni++) {
      int col = n0 + wc * 64 + ni * 16 + lq;
      if (EPI == 0) {
        float s = (col < 1024) ? qscale : 1.0f;
#pragma unroll
        for (int r = 0; r < 4; r++) {
          int row = m0 + wr * 64 + mi * 16 + quad * 4 + r;
          Cb[(size_t)row * N + col] = __float2bfloat16(acc[mi][ni][r] * s);
        }
      } else {
        float bv = bias[col];
#pragma unroll
        for (int r = 0; r < 4; r++) {
          int row = m0 + wr * 64 + mi * 16 + quad * 4 + r;
          Cf[(size_t)row * N + col] = acc[mi][ni][r] + bv;
        }
      }
    }
  }
}

// ---------------- flash attention: register-only, 2 q-bands/wave ----------------
// Block = 128 q-rows (q-tile pair 2j,2j+1). Wave w: tile qt=2j+(w>>1), rows
// (w&1)*32 + {0,16} within the tile. Same K/V fragment loads serve both bands
// -> 2x arithmetic intensity vs R6. Heavy-first dispatch (j = 15 - blockIdx.x).
__launch_bounds__(256, 3)
__global__ void attn(const __hip_bfloat16* __restrict__ qkv,
                     const __hip_bfloat16* __restrict__ kpack,
                     const __hip_bfloat16* __restrict__ vpack,
                     __hip_bfloat16* __restrict__ obuf) {
  const int tid = threadIdx.x;
  const int w = tid >> 6, lane = tid & 63;
  const int lq = lane & 15, quad = lane >> 4;

  const int j = 15 - (int)blockIdx.x;        // heavy pairs first
  const int bh = blockIdx.y;
  const int b = bh >> 4, h = bh & 15;
  const int qt = 2 * j + (w >> 1);           // this wave's q-tile
  const int rbase = (w & 1) * 32;            // row base within tile

  // Q fragments for 2 bands: B-operand B[n=lq -> t][k=quad*8+j]
  short8 qf[2][2];
#pragma unroll
  for (int bi = 0; bi < 2; bi++) {
    const __hip_bfloat16* qp =
        qkv + ((size_t)(b * T_ + qt * 64 + rbase + bi * 16 + lq)) * NQKV + h * HD_;
    qf[bi][0] = *(const short8*)(qp + quad * 8);
    qf[bi][1] = *(const short8*)(qp + 32 + quad * 8);
  }

  floatx4 Oacc[2][4];
#pragma unroll
  for (int bi = 0; bi < 2; bi++)
#pragma unroll
    for (int i = 0; i < 4; i++) Oacc[bi][i] = (floatx4){0.f, 0.f, 0.f, 0.f};
  float lrow[2] = {0.f, 0.f};

  const __hip_bfloat16* kb = kpack + ((size_t)bh * NST) * 4096 + lane * 8;
  const __hip_bfloat16* vb = vpack + ((size_t)bh * NST) * 4096 + lane * 8;

  const int nIter = qt + 1;                  // wave loops to its own diagonal
  for (int it = 0; it < nIter; ++it) {
    short8 kf[4], kg[4];
#pragma unroll
    for (int ni = 0; ni < 4; ni++) {
      kf[ni] = *(const short8*)(kb + (size_t)(ni * 2 + 0) * 512);
      kg[ni] = *(const short8*)(kb + (size_t)(ni * 2 + 1) * 512);
    }
    short8 vfr[8];
#pragma unroll
    for (int c = 0; c < 8; c++) vfr[c] = *(const short8*)(vb + (size_t)c * 512);

    // S^T = K Q^T for both bands (exp2 domain)
    floatx4 Sc[2][4];
#pragma unroll
    for (int bi = 0; bi < 2; bi++)
#pragma unroll
      for (int ni = 0; ni < 4; ni++) {
        floatx4 c0 = (floatx4){0.f, 0.f, 0.f, 0.f};
        c0 = __builtin_amdgcn_mfma_f32_16x16x32_bf16(kf[ni], qf[bi][0], c0, 0, 0, 0);
        c0 = __builtin_amdgcn_mfma_f32_16x16x32_bf16(kg[ni], qf[bi][1], c0, 0, 0, 0);
        Sc[bi][ni] = c0;   // reg r: s = ni*16 + quad*4 + r, t = lq (band bi)
      }

    // causal mask on the wave's diagonal tile
    if (it == nIter - 1) {
#pragma unroll
      for (int bi = 0; bi < 2; bi++) {
        int lrow_idx = rbase + bi * 16 + lq;
#pragma unroll
        for (int ni = 0; ni < 4; ni++)
#pragma unroll
          for (int r = 0; r < 4; r++) {
            int s_loc = ni * 16 + quad * 4 + r;
            if (s_loc > lrow_idx) Sc[bi][ni][r] = -__builtin_inff();
          }
      }
    }

    // p = exp2(S); per-lane row sums; pack to PV A-frags (C-layout == A-layout for S^T)
    bf16x4 pf[2][4];
#pragma unroll
    for (int bi = 0; bi < 2; bi++)
#pragma unroll
      for (int c = 0; c < 4; c++) {
        __hip_bfloat16 pb[4];
#pragma unroll
        for (int r = 0; r < 4; r++) {
          float p = __builtin_amdgcn_exp2f(Sc[bi][c][r]);
          lrow[bi] += p;
          pb[r] = __float2bfloat16(p);
        }
        pf[bi][c] = *(bf16x4*)pb;
      }

    // O += P V  (both bands share the V fragments)
#pragma unroll
    for (int m = 0; m < 2; m++)
#pragma unroll
      for (int nt = 0; nt < 4; nt++) {
        short8 v8 = vfr[m * 4 + nt];
        bf16x4 vlo = (bf16x4){v8[0], v8[1], v8[2], v8[3]};
        bf16x4 vhi = (bf16x4){v8[4], v8[5], v8[6], v8[7]};
#pragma unroll
        for (int bi = 0; bi < 2; bi++) {
          Oacc[bi][nt] = mfma16(pf[bi][2 * m + 0], vlo, Oacc[bi][nt]);
          Oacc[bi][nt] = mfma16(pf[bi][2 * m + 1], vhi, Oacc[bi][nt]);
        }
      }

    kb += 4096;
    vb += 4096;
  }

  // epilogue per band: reduce lrow across quads, normalize, store
#pragma unroll
  for (int bi = 0; bi < 2; bi++) {
    float ps = lrow[bi];
    ps += __shfl_xor(ps, 16);
    ps += __shfl_xor(ps, 32);
    float inv = 1.0f / ps;                    // valid for t = lq in every lane
#pragma unroll
    for (int r = 0; r < 4; r++) {
      float invr = __shfl(inv, quad * 4 + r); // inv for t = quad*4+r
      int t = qt * 64 + rbase + bi * 16 + quad * 4 + r;
#pragma unroll
      for (int nt = 0; nt < 4; nt++)
        obuf[(size_t)(b * T_ + t) * D_ + h * HD_ + nt * 16 + lq] =
            __float2bfloat16(Oacc[bi][nt][r] * invr);
    }
  }
}

// ---------------- launch ----------------

extern "C" void kernel_launch(void* const* d_in, const int* in_sizes, int n_in,
                              void* d_out, int out_size, void* d_ws, size_t ws_size,
                              hipStream_t stream) {
  const float* x  = (const float*)d_in[0];
  const float* Wq = (const float*)d_in[1];
  const float* Wk = (const float*)d_in[2];
  const float* Wv = (const float*)d_in[3];
  const float* Wo = (const float*)d_in[4];
  const float* bo = (const float*)d_in[5];
  float* out = (float*)d_out;

  char* ws = (char*)d_ws;
  __hip_bfloat16* xb    = (__hip_bfloat16*)(ws);                          // 16 MB (dead after QKV gemm)
  __hip_bfloat16* obuf  = (__hip_bfloat16*)(ws);                          // reuses xb's slot
  __hip_bfloat16* wqkv  = (__hip_bfloat16*)(ws + ((size_t)16 << 20));     //  6 MB
  __hip_bfloat16* wob   = (__hip_bfloat16*)(ws + ((size_t)22 << 20));     //  2 MB
  __hip_bfloat16* qkv   = (__hip_bfloat16*)(ws + ((size_t)24 << 20));     // 48 MB
  __hip_bfloat16* kpack = (__hip_bfloat16*)(ws + ((size_t)72 << 20));     // 16 MB
  __hip_bfloat16* vpack = (__hip_bfloat16*)(ws + ((size_t)88 << 20));     // 16 MB

  convert_bf16<<<(MROWS * D_) / 1024, 256, 0, stream>>>(x, xb, MROWS * D_);
  convert_bf16<<<(D_ * D_) / 1024, 256, 0, stream>>>(Wo, wob, D_ * D_);
  transpose_w<<<dim3(16, 48), 256, 0, stream>>>(Wq, Wk, Wv, wqkv);

  // qkv = xb * wqkv^T   (q columns pre-scaled by log2e/8)
  gemm_bt<0><<<dim3(MROWS / 128, NQKV / 128), 256, 0, stream>>>(
      xb, wqkv, qkv, nullptr, nullptr, MROWS, NQKV, D_, QSCALE);

  repack_kv<<<dim3(NST, B_ * H_), 256, 0, stream>>>(qkv, kpack, vpack);

  attn<<<dim3(16, B_ * H_), 256, 0, stream>>>(qkv, kpack, vpack, obuf);

  // out = obuf * Wo^T + bo
  gemm_bt<1><<<dim3(MROWS / 128, D_ / 128), 256, 0, stream>>>(
      obuf, wob, nullptr, out, bo, MROWS, D_, D_, 1.0f);
}

// Round 8
// 249.709 us; speedup vs baseline: 1.1712x; 1.1712x over previous
//
#include <hip/hip_runtime.h>
#include <hip/hip_bf16.h>
#include <stdint.h>

#define B_   4
#define T_   2048
#define D_   1024
#define H_   16
#define HD_  64
#define MROWS (B_*T_)      // 8192
#define NQKV  3072
#define NST  (T_/64)       // 32 s-tiles per head

typedef __attribute__((ext_vector_type(8))) short  short8;   // 8 x bf16
typedef __attribute__((ext_vector_type(4))) short  bf16x4;   // 4 x bf16 (avoid HIP's short4)
typedef __attribute__((ext_vector_type(4))) float  floatx4;

#define QSCALE 0.1803368801111244f   // log2(e)/sqrt(64)

__device__ inline void async_copy16(const __hip_bfloat16* g, __hip_bfloat16* l) {
  __builtin_amdgcn_global_load_lds(
      (const __attribute__((address_space(1))) void*)g,
      (__attribute__((address_space(3))) void*)l, 16, 0, 0);
}

// K=16 bf16 MFMA (gfx950: ..._16x16x16bf16_1k; fallback keeps it compiling)
__device__ inline floatx4 mfma16(bf16x4 a, bf16x4 b, floatx4 c) {
#if __has_builtin(__builtin_amdgcn_mfma_f32_16x16x16bf16_1k)
  return __builtin_amdgcn_mfma_f32_16x16x16bf16_1k(a, b, c, 0, 0, 0);
#elif __has_builtin(__builtin_amdgcn_mfma_f32_16x16x16_bf16)
  return __builtin_amdgcn_mfma_f32_16x16x16_bf16(a, b, c, 0, 0, 0);
#else
  short8 a8 = (short8){a[0], a[1], a[2], a[3], 0, 0, 0, 0};
  short8 b8 = (short8){b[0], b[1], b[2], b[3], 0, 0, 0, 0};
  return __builtin_amdgcn_mfma_f32_16x16x32_bf16(a8, b8, c, 0, 0, 0);
#endif
}

// ---------------- conversion kernels ----------------

__global__ void convert_bf16(const float* __restrict__ in, __hip_bfloat16* __restrict__ out, int n) {
  int i = (blockIdx.x * blockDim.x + threadIdx.x) * 4;
  if (i < n) {
    float4 v = *(const float4*)(in + i);
    out[i + 0] = __float2bfloat16(v.x);
    out[i + 1] = __float2bfloat16(v.y);
    out[i + 2] = __float2bfloat16(v.z);
    out[i + 3] = __float2bfloat16(v.w);
  }
}

__global__ void transpose_w(const float* __restrict__ Wq, const float* __restrict__ Wk,
                            const float* __restrict__ Wv, __hip_bfloat16* __restrict__ wqkv) {
  __shared__ __hip_bfloat16 tile[64][65];
  const int t = threadIdx.x;
  const int d0 = blockIdx.x * 64;
  const int wh = blockIdx.y;           // 0..47
  const int which = wh >> 4, h = wh & 15;
  const float* W = (which == 0) ? Wq : ((which == 1) ? Wk : Wv);
  const float* base = W + (size_t)h * D_ * HD_;
#pragma unroll
  for (int i = 0; i < 16; i++) {
    int e = i * 256 + t;
    int dr = e >> 6, hd = e & 63;
    tile[dr][hd] = __float2bfloat16(base[(size_t)(d0 + dr) * HD_ + hd]);
  }
  __syncthreads();
#pragma unroll
  for (int i = 0; i < 16; i++) {
    int e = i * 256 + t;
    int hd = e >> 6, dr = e & 63;
    wqkv[(size_t)(which * 1024 + h * 64 + hd) * D_ + d0 + dr] = tile[dr][hd];
  }
}

// ---------------- repack K,V into fragment-contiguous tiles ----------------
__global__ void repack_kv(const __hip_bfloat16* __restrict__ qkv,
                          __hip_bfloat16* __restrict__ kpack, __hip_bfloat16* __restrict__ vpack) {
  __shared__ __hip_bfloat16 Ks[64][72];
  __shared__ __hip_bfloat16 Vs[64][72];
  const int tid = threadIdx.x;
  const int st = blockIdx.x, bh = blockIdx.y;
  const int b = bh >> 4, h = bh & 15;
#pragma unroll
  for (int p = 0; p < 2; p++) {
    int c = p * 256 + tid;           // 512 chunks of 16B per matrix
    int row = c >> 3, col8 = c & 7;
    const __hip_bfloat16* src = qkv + (size_t)(b * T_ + st * 64 + row) * NQKV + h * HD_ + col8 * 8;
    *(uint4*)&Ks[row][col8 * 8] = *(const uint4*)(src + 1024);
    *(uint4*)&Vs[row][col8 * 8] = *(const uint4*)(src + 2048);
  }
  __syncthreads();
  const size_t base = ((size_t)bh * NST + st) * 8 * 512;
#pragma unroll
  for (int p = 0; p < 2; p++) {
    int pair = p * 256 + tid;        // 8 chunks x 64 lanes
    int c = pair >> 6, l = pair & 63;
    int lq = l & 15, q = l >> 4;
    int ni = c >> 1, half = c & 1;
    short8 v = *(const short8*)&Ks[ni * 16 + lq][half * 32 + q * 8];
    *(short8*)(kpack + base + (size_t)c * 512 + l * 8) = v;
  }
#pragma unroll
  for (int p = 0; p < 2; p++) {
    int pair = p * 256 + tid;
    int c = pair >> 6, l = pair & 63;
    int lq = l & 15, q = l >> 4;
    int m = c >> 2, nt = c & 3;
    __hip_bfloat16 tmp[8];
#pragma unroll
    for (int half = 0; half < 2; half++)
#pragma unroll
      for (int j = 0; j < 4; j++)
        tmp[half * 4 + j] = Vs[(2 * m + half) * 16 + q * 4 + j][nt * 16 + lq];
    *(short8*)(vpack + base + (size_t)c * 512 + l * 8) = *(short8*)tmp;
  }
}

// ---------------- GEMM: C = A[M,K] * Bt[N,K]^T ----------------
template <int EPI>
__launch_bounds__(256, 2)
__global__ void gemm_bt(const __hip_bfloat16* __restrict__ A, const __hip_bfloat16* __restrict__ Bt,
                        __hip_bfloat16* __restrict__ Cb, float* __restrict__ Cf,
                        const float* __restrict__ bias, int M, int N, int K, float qscale) {
  __shared__ __hip_bfloat16 As[128 * 32];
  __shared__ __hip_bfloat16 Bs[128 * 32];
  const int tid = threadIdx.x;
  const int w = tid >> 6, lane = tid & 63;
  const int lq = lane & 15, quad = lane >> 4;
  const int wr = w >> 1, wc = w & 1;
  const int m0 = blockIdx.x * 128, n0 = blockIdx.y * 128;

  floatx4 acc[4][4];
#pragma unroll
  for (int i = 0; i < 4; i++)
#pragma unroll
    for (int j = 0; j < 4; j++) acc[i][j] = (floatx4){0.f, 0.f, 0.f, 0.f};

  for (int k0 = 0; k0 < K; k0 += 32) {
    __syncthreads();
#pragma unroll
    for (int ph = 0; ph < 2; ++ph) {
      int c = ph * 256 + tid;
      int row = c >> 2, col8 = c & 3;
      async_copy16(A + (size_t)(m0 + row) * K + k0 + col8 * 8, As + c * 8);
      async_copy16(Bt + (size_t)(n0 + row) * K + k0 + col8 * 8, Bs + c * 8);
    }
    __syncthreads();
    short8 af[4], bf[4];
#pragma unroll
    for (int mi = 0; mi < 4; mi++)
      af[mi] = *(const short8*)(As + (wr * 64 + mi * 16 + lq) * 32 + quad * 8);
#pragma unroll
    for (int ni = 0; ni < 4; ni++)
      bf[ni] = *(const short8*)(Bs + (wc * 64 + ni * 16 + lq) * 32 + quad * 8);
#pragma unroll
    for (int mi = 0; mi < 4; mi++)
#pragma unroll
      for (int ni = 0; ni < 4; ni++)
        acc[mi][ni] = __builtin_amdgcn_mfma_f32_16x16x32_bf16(af[mi], bf[ni], acc[mi][ni], 0, 0, 0);
  }

#pragma unroll
  for (int mi = 0; mi < 4; mi++) {
#pragma unroll
    for (int ni = 0; ni < 4; ni++) {
      int col = n0 + wc * 64 + ni * 16 + lq;
      if (EPI == 0) {
        float s = (col < 1024) ? qscale : 1.0f;
#pragma unroll
        for (int r = 0; r < 4; r++) {
          int row = m0 + wr * 64 + mi * 16 + quad * 4 + r;
          Cb[(size_t)row * N + col] = __float2bfloat16(acc[mi][ni][r] * s);
        }
      } else {
        float bv = bias[col];
#pragma unroll
        for (int r = 0; r < 4; r++) {
          int row = m0 + wr * 64 + mi * 16 + quad * 4 + r;
          Cf[(size_t)row * N + col] = acc[mi][ni][r] + bv;
        }
      }
    }
  }
}

// ---------------- flash attention: 2 bands/wave, balanced segments, XCD-local ----------------
// Block (bh, a): seg0 = tiles (2a, 2a+1), seg1 = tiles (30-2a, 31-2a).
// Max iters/block = (2a+2)+(32-2a) = 34 uniform -> zero tail; 512 blocks all
// co-resident at 2 blocks/CU. grid(64,8): linear%8 = bh%8 -> one bh per XCD L2.
__launch_bounds__(256, 2)
__global__ void attn(const __hip_bfloat16* __restrict__ qkv,
                     const __hip_bfloat16* __restrict__ kpack,
                     const __hip_bfloat16* __restrict__ vpack,
                     __hip_bfloat16* __restrict__ obuf) {
  const int tid = threadIdx.x;
  const int w = tid >> 6, lane = tid & 63;
  const int lq = lane & 15, quad = lane >> 4;

  const int bh = (int)blockIdx.x;            // XCD = bh % 8
  const int a  = (int)blockIdx.y;            // 0..7
  const int b = bh >> 4, h = bh & 15;

  const __hip_bfloat16* kb0 = kpack + ((size_t)bh * NST) * 4096 + lane * 8;
  const __hip_bfloat16* vb0 = vpack + ((size_t)bh * NST) * 4096 + lane * 8;

#pragma unroll 1
  for (int seg = 0; seg < 2; ++seg) {
    const int tbase = seg ? (NST - 2 - 2 * a) : (2 * a);
    const int qt = tbase + (w >> 1);         // this wave's q-tile
    const int rbase = (w & 1) * 32;          // row base within tile

    // Q fragments for 2 bands: B-operand B[n=lq -> t][k=quad*8+j]
    short8 qf[2][2];
#pragma unroll
    for (int bi = 0; bi < 2; bi++) {
      const __hip_bfloat16* qp =
          qkv + ((size_t)(b * T_ + qt * 64 + rbase + bi * 16 + lq)) * NQKV + h * HD_;
      qf[bi][0] = *(const short8*)(qp + quad * 8);
      qf[bi][1] = *(const short8*)(qp + 32 + quad * 8);
    }

    floatx4 Oacc[2][4];
#pragma unroll
    for (int bi = 0; bi < 2; bi++)
#pragma unroll
      for (int i = 0; i < 4; i++) Oacc[bi][i] = (floatx4){0.f, 0.f, 0.f, 0.f};
    float lrow[2] = {0.f, 0.f};

    const __hip_bfloat16* kb = kb0;
    const __hip_bfloat16* vb = vb0;
    const int nIter = qt + 1;                // wave loops to its own diagonal
    for (int it = 0; it < nIter; ++it) {
      short8 kf[4], kg[4];
#pragma unroll
      for (int ni = 0; ni < 4; ni++) {
        kf[ni] = *(const short8*)(kb + (size_t)(ni * 2 + 0) * 512);
        kg[ni] = *(const short8*)(kb + (size_t)(ni * 2 + 1) * 512);
      }
      short8 vfr[8];
#pragma unroll
      for (int c = 0; c < 8; c++) vfr[c] = *(const short8*)(vb + (size_t)c * 512);

      // S^T = K Q^T for both bands (exp2 domain)
      floatx4 Sc[2][4];
#pragma unroll
      for (int bi = 0; bi < 2; bi++)
#pragma unroll
        for (int ni = 0; ni < 4; ni++) {
          floatx4 c0 = (floatx4){0.f, 0.f, 0.f, 0.f};
          c0 = __builtin_amdgcn_mfma_f32_16x16x32_bf16(kf[ni], qf[bi][0], c0, 0, 0, 0);
          c0 = __builtin_amdgcn_mfma_f32_16x16x32_bf16(kg[ni], qf[bi][1], c0, 0, 0, 0);
          Sc[bi][ni] = c0;   // reg r: s = ni*16 + quad*4 + r, t = lq (band bi)
        }

      // causal mask on the wave's diagonal tile
      if (it == nIter - 1) {
#pragma unroll
        for (int bi = 0; bi < 2; bi++) {
          int lrow_idx = rbase + bi * 16 + lq;
#pragma unroll
          for (int ni = 0; ni < 4; ni++)
#pragma unroll
            for (int r = 0; r < 4; r++) {
              int s_loc = ni * 16 + quad * 4 + r;
              if (s_loc > lrow_idx) Sc[bi][ni][r] = -__builtin_inff();
            }
        }
      }

      // p = exp2(S); per-lane row sums; pack to PV A-frags
      bf16x4 pf[2][4];
#pragma unroll
      for (int bi = 0; bi < 2; bi++)
#pragma unroll
        for (int c = 0; c < 4; c++) {
          __hip_bfloat16 pb[4];
#pragma unroll
          for (int r = 0; r < 4; r++) {
            float p = __builtin_amdgcn_exp2f(Sc[bi][c][r]);
            lrow[bi] += p;
            pb[r] = __float2bfloat16(p);
          }
          pf[bi][c] = *(bf16x4*)pb;
        }

      // O += P V  (both bands share the V fragments)
#pragma unroll
      for (int m = 0; m < 2; m++)
#pragma unroll
        for (int nt = 0; nt < 4; nt++) {
          short8 v8 = vfr[m * 4 + nt];
          bf16x4 vlo = (bf16x4){v8[0], v8[1], v8[2], v8[3]};
          bf16x4 vhi = (bf16x4){v8[4], v8[5], v8[6], v8[7]};
#pragma unroll
          for (int bi = 0; bi < 2; bi++) {
            Oacc[bi][nt] = mfma16(pf[bi][2 * m + 0], vlo, Oacc[bi][nt]);
            Oacc[bi][nt] = mfma16(pf[bi][2 * m + 1], vhi, Oacc[bi][nt]);
          }
        }

      kb += 4096;
      vb += 4096;
    }

    // epilogue per band: reduce lrow across quads, normalize, store
#pragma unroll
    for (int bi = 0; bi < 2; bi++) {
      float ps = lrow[bi];
      ps += __shfl_xor(ps, 16);
      ps += __shfl_xor(ps, 32);
      float inv = 1.0f / ps;                    // valid for t = lq in every lane
#pragma unroll
      for (int r = 0; r < 4; r++) {
        float invr = __shfl(inv, quad * 4 + r); // inv for t = quad*4+r
        int t = qt * 64 + rbase + bi * 16 + quad * 4 + r;
#pragma unroll
        for (int nt = 0; nt < 4; nt++)
          obuf[(size_t)(b * T_ + t) * D_ + h * HD_ + nt * 16 + lq] =
              __float2bfloat16(Oacc[bi][nt][r] * invr);
      }
    }
  }
}

// ---------------- launch ----------------

extern "C" void kernel_launch(void* const* d_in, const int* in_sizes, int n_in,
                              void* d_out, int out_size, void* d_ws, size_t ws_size,
                              hipStream_t stream) {
  const float* x  = (const float*)d_in[0];
  const float* Wq = (const float*)d_in[1];
  const float* Wk = (const float*)d_in[2];
  const float* Wv = (const float*)d_in[3];
  const float* Wo = (const float*)d_in[4];
  const float* bo = (const float*)d_in[5];
  float* out = (float*)d_out;

  char* ws = (char*)d_ws;
  __hip_bfloat16* xb    = (__hip_bfloat16*)(ws);                          // 16 MB (dead after QKV gemm)
  __hip_bfloat16* obuf  = (__hip_bfloat16*)(ws);                          // reuses xb's slot
  __hip_bfloat16* wqkv  = (__hip_bfloat16*)(ws + ((size_t)16 << 20));     //  6 MB
  __hip_bfloat16* wob   = (__hip_bfloat16*)(ws + ((size_t)22 << 20));     //  2 MB
  __hip_bfloat16* qkv   = (__hip_bfloat16*)(ws + ((size_t)24 << 20));     // 48 MB
  __hip_bfloat16* kpack = (__hip_bfloat16*)(ws + ((size_t)72 << 20));     // 16 MB
  __hip_bfloat16* vpack = (__hip_bfloat16*)(ws + ((size_t)88 << 20));     // 16 MB

  convert_bf16<<<(MROWS * D_) / 1024, 256, 0, stream>>>(x, xb, MROWS * D_);
  convert_bf16<<<(D_ * D_) / 1024, 256, 0, stream>>>(Wo, wob, D_ * D_);
  transpose_w<<<dim3(16, 48), 256, 0, stream>>>(Wq, Wk, Wv, wqkv);

  // qkv = xb * wqkv^T   (q columns pre-scaled by log2e/8)
  gemm_bt<0><<<dim3(MROWS / 128, NQKV / 128), 256, 0, stream>>>(
      xb, wqkv, qkv, nullptr, nullptr, MROWS, NQKV, D_, QSCALE);

  repack_kv<<<dim3(NST, B_ * H_), 256, 0, stream>>>(qkv, kpack, vpack);

  attn<<<dim3(B_ * H_, 8), 256, 0, stream>>>(qkv, kpack, vpack, obuf);

  // out = obuf * Wo^T + bo
  gemm_bt<1><<<dim3(MROWS / 128, D_ / 128), 256, 0, stream>>>(
      obuf, wob, nullptr, out, bo, MROWS, D_, D_, 1.0f);
}